// Round 1
// baseline (461.720 us; speedup 1.0000x reference)
//
#include <hip/hip_runtime.h>
#include <cstdint>
#include <cstddef>

// ---------------------------------------------------------------------------
// SparseAttention (BigBird-style) on MI355X.
// Pipeline: cast->bf16, QKV GEMMs (MFMA 16x16x32 bf16, 128x128 tiles,
// global_load_lds staging, xor-swizzled LDS), fused block-sparse attention,
// out-proj GEMM with bias+residual epilogue, LayerNorm.
// Shapes fixed by the problem: b=4, s=4096, HIDDEN=1024, heads=16, hd=64,
// BLOCK=64, nblk=64, key-blocks/query-block = 4 (global 0 + window i-1,i,i+1).
// ---------------------------------------------------------------------------

using f32x4 = __attribute__((ext_vector_type(4))) float;
using s16x8 = __attribute__((ext_vector_type(8))) short;
using u16x4 = __attribute__((ext_vector_type(4))) unsigned short;

#define NEGV -1000000000.0f

__device__ __forceinline__ unsigned short f2b(float f) {
  unsigned u = __float_as_uint(f);
  u += 0x7FFFu + ((u >> 16) & 1u);   // round-to-nearest-even
  return (unsigned short)(u >> 16);
}

#define GLDS(g, l)                                                        \
  __builtin_amdgcn_global_load_lds(                                       \
      (__attribute__((address_space(1))) void*)(g),                       \
      (__attribute__((address_space(3))) void*)(l), 16, 0, 0)

// ------------------------------- casts -------------------------------------
__global__ __launch_bounds__(256) void cast_hidden(const float* __restrict__ in,
                                                   unsigned short* __restrict__ out) {
  size_t i = (size_t)blockIdx.x * 256 + threadIdx.x;
  float4 v = ((const float4*)in)[i];
  u16x4 o = {f2b(v.x), f2b(v.y), f2b(v.z), f2b(v.w)};
  ((u16x4*)out)[i] = o;
}

__global__ __launch_bounds__(256) void cast_weights(const float* __restrict__ w0,
                                                    const float* __restrict__ w1,
                                                    const float* __restrict__ w2,
                                                    const float* __restrict__ w3,
                                                    unsigned short* __restrict__ out) {
  const float* src = blockIdx.y == 0 ? w0 : blockIdx.y == 1 ? w1 : blockIdx.y == 2 ? w2 : w3;
  size_t i = (size_t)blockIdx.x * 256 + threadIdx.x;
  float4 v = ((const float4*)src)[i];
  u16x4 o = {f2b(v.x), f2b(v.y), f2b(v.z), f2b(v.w)};
  ((u16x4*)(out + (size_t)blockIdx.y * 1048576))[i] = o;
}

// ------------------------------- GEMM --------------------------------------
// C[m,n] = sum_k A[m,k]*B[n,k] + bias[n]   (A: [M,1024] bf16, B: [1024,1024] bf16)
// MODE 0: write bf16 scattered to [b][h][s][d] (QKV).  MODE 1: +resid, fp32 out.
template <int MODE>
__global__ __launch_bounds__(256) void gemm128(const unsigned short* __restrict__ A,
                                               const unsigned short* __restrict__ B,
                                               const float* __restrict__ bias,
                                               const float* __restrict__ resid,
                                               void* __restrict__ outp) {
  __shared__ __align__(16) unsigned short As[4096];  // 128 x 32 bf16
  __shared__ __align__(16) unsigned short Bs[4096];
  const int t = threadIdx.x;
  const int wave = t >> 6, lane = t & 63;
  const int quad = lane >> 4, lr = lane & 15;
  const int wm = (wave >> 1) << 6, wn = (wave & 1) << 6;
  const int bm = blockIdx.x << 7, bn = blockIdx.y << 7;

  f32x4 acc[4][4] = {};

  // staging: thread t covers rows (t>>2) and (t>>2)+64, 16B chunk (t&3),
  // xor-swizzled so ds_read_b128 fragment reads are conflict-free.
  const int srow = t >> 2;
  const int sq = (t & 3) ^ ((srow >> 1) & 3);  // same for both row halves (64 = 0 mod 4 after >>1)
  const char* Ag = (const char*)A + (((size_t)(bm + srow)) << 11) + (sq << 4);
  const char* Bg = (const char*)B + (((size_t)(bn + srow)) << 11) + (sq << 4);
  char* AsW = (char*)As + (t << 4);
  char* BsW = (char*)Bs + (t << 4);

  for (int kt = 0; kt < 2048; kt += 64) {  // kt = K-offset in bytes (32 bf16 / iter)
    __syncthreads();
    GLDS(Ag + kt, AsW);
    GLDS(Ag + kt + (64ll << 11), AsW + 4096);
    GLDS(Bg + kt, BsW);
    GLDS(Bg + kt + (64ll << 11), BsW + 4096);
    __syncthreads();
    s16x8 af[4], bf[4];
#pragma unroll
    for (int i = 0; i < 4; ++i) {
      const int ra = wm + i * 16 + lr;
      af[i] = *(const s16x8*)((const char*)As + ra * 64 + ((quad ^ ((ra >> 1) & 3)) << 4));
      const int rb = wn + i * 16 + lr;
      bf[i] = *(const s16x8*)((const char*)Bs + rb * 64 + ((quad ^ ((rb >> 1) & 3)) << 4));
    }
#pragma unroll
    for (int i = 0; i < 4; ++i)
#pragma unroll
      for (int j = 0; j < 4; ++j)
        acc[i][j] = __builtin_amdgcn_mfma_f32_16x16x32_bf16(af[i], bf[j], acc[i][j], 0, 0, 0);
  }

  float bv[4];
#pragma unroll
  for (int j = 0; j < 4; ++j) bv[j] = bias[bn + wn + j * 16 + lr];

  if (MODE == 0) {
    unsigned short* o = (unsigned short*)outp;
    int hh[4], dd[4];
#pragma unroll
    for (int j = 0; j < 4; ++j) {
      int n = bn + wn + j * 16 + lr;
      hh[j] = n >> 6;
      dd[j] = n & 63;
    }
#pragma unroll
    for (int i = 0; i < 4; ++i) {
#pragma unroll
      for (int r = 0; r < 4; ++r) {
        int m = bm + wm + i * 16 + quad * 4 + r;  // C/D: row = quad*4+reg, col = lr
        int bb = m >> 12, sl = m & 4095;
        size_t base = ((size_t)bb * 16) * 262144 + (size_t)sl * 64;
#pragma unroll
        for (int j = 0; j < 4; ++j)
          o[base + (size_t)hh[j] * 262144 + dd[j]] = f2b(acc[i][j][r] + bv[j]);
      }
    }
  } else {
    float* o = (float*)outp;
#pragma unroll
    for (int i = 0; i < 4; ++i) {
#pragma unroll
      for (int r = 0; r < 4; ++r) {
        size_t m = bm + wm + i * 16 + quad * 4 + r;
        const float* rr = resid + m * 1024 + bn + wn;
        float* orow = o + m * 1024 + bn + wn;
#pragma unroll
        for (int j = 0; j < 4; ++j)
          orow[j * 16 + lr] = acc[i][j][r] + bv[j] + rr[j * 16 + lr];
      }
    }
  }
}

// ----------------------------- attention -----------------------------------
// grid (qi=64, h=16, b=4), 256 threads. Q/K/V bf16 in [b][h][s][d].
// Wave w handles key-block c=w for QK^T; softmax in registers + LDS combine;
// P -> LDS (A-layout), V -> LDS transposed; PV per-wave over 16 query rows.
__global__ __launch_bounds__(256) void attn(const unsigned short* __restrict__ Q,
                                            const unsigned short* __restrict__ K,
                                            const unsigned short* __restrict__ V,
                                            const float* __restrict__ amask,
                                            unsigned short* __restrict__ ctx) {
  __shared__ __align__(16) char smem[70656];
  char* Qs = smem;            // [64][72 bf16] rowstride 144B   (phase 1)
  char* Ks = smem + 9216;     // 4 x [64][72]                    (phase 1)
  char* Pb = smem;            // [64][264 bf16] rowstride 528B   (phase 2)
  char* Vt = smem + 33792;    // [64 d][264 key] rowstride 528B  (phase 2)
  float* maskL = (float*)(smem + 67584);  // [256]
  float* wmaxL = (float*)(smem + 68608);  // [64][4]
  float* wsumL = (float*)(smem + 69632);  // [64][4]

  const int qi = blockIdx.x, h = blockIdx.y, b = blockIdx.z;
  const int t = threadIdx.x;
  const int wave = t >> 6, lane = t & 63;
  const int quad = lane >> 4, lr = lane & 15;

  // bigbird layout: key blocks {0, qi-1, qi, qi+1}; window slot valid iff 1<=cand<64
  int kb[4], kv[4];
  kb[0] = 0; kv[0] = 1;
#pragma unroll
  for (int c = 1; c < 4; ++c) {
    int cand = qi - 2 + c;
    kv[c] = (cand >= 1 && cand < 64);
    kb[c] = cand < 0 ? 0 : (cand > 63 ? 63 : cand);
  }

  const size_t bh = ((size_t)b * 16 + h) * 262144;
  const unsigned short* Qg = Q + bh + (size_t)qi * 4096;

  {  // stage Q (64 rows x 128B) and K (4 blocks)
    int row = t >> 3, ch = t & 7;
    *(s16x8*)(Qs + row * 144 + ch * 16) = *(const s16x8*)((const char*)Qg + row * 128 + ch * 16);
    *(s16x8*)(Qs + (row + 32) * 144 + ch * 16) =
        *(const s16x8*)((const char*)Qg + (row + 32) * 128 + ch * 16);
#pragma unroll
    for (int c = 0; c < 4; ++c) {
      const unsigned short* Kg = K + bh + (size_t)kb[c] * 4096;
      char* Kc = Ks + c * 9216;
      *(s16x8*)(Kc + row * 144 + ch * 16) = *(const s16x8*)((const char*)Kg + row * 128 + ch * 16);
      *(s16x8*)(Kc + (row + 32) * 144 + ch * 16) =
          *(const s16x8*)((const char*)Kg + (row + 32) * 128 + ch * 16);
    }
  }
  {  // mask + validity
    int c = t >> 6, kk = t & 63;
    float mv = amask[(size_t)b * 4096 + kb[c] * 64 + kk];
    maskL[c * 64 + kk] = kv[c] ? mv : mv + NEGV;
  }
  __syncthreads();

  // ---- QK^T: wave's key block c = wave ----
  f32x4 s[4][4] = {};
  const char* Kc = Ks + wave * 9216;
#pragma unroll
  for (int ks = 0; ks < 2; ++ks) {
    s16x8 af[4], bf[4];
#pragma unroll
    for (int i = 0; i < 4; ++i) {
      af[i] = *(const s16x8*)(Qs + (i * 16 + lr) * 144 + ks * 64 + quad * 16);
      bf[i] = *(const s16x8*)(Kc + (i * 16 + lr) * 144 + ks * 64 + quad * 16);
    }
#pragma unroll
    for (int i = 0; i < 4; ++i)
#pragma unroll
      for (int j = 0; j < 4; ++j)
        s[i][j] = __builtin_amdgcn_mfma_f32_16x16x32_bf16(af[i], bf[j], s[i][j], 0, 0, 0);
  }
  // scale + mask (in place)
#pragma unroll
  for (int j = 0; j < 4; ++j) {
    const float mj = maskL[wave * 64 + j * 16 + lr];
#pragma unroll
    for (int i = 0; i < 4; ++i)
#pragma unroll
      for (int r = 0; r < 4; ++r) s[i][j][r] = s[i][j][r] * 0.125f + mj;
  }
  __syncthreads();  // Q/K LDS now dead; P/Vt may overwrite

  // wave-local row max -> wmaxL
#pragma unroll
  for (int i = 0; i < 4; ++i)
#pragma unroll
    for (int r = 0; r < 4; ++r) {
      float m0 = fmaxf(fmaxf(s[i][0][r], s[i][1][r]), fmaxf(s[i][2][r], s[i][3][r]));
      m0 = fmaxf(m0, __shfl_xor(m0, 1, 64));
      m0 = fmaxf(m0, __shfl_xor(m0, 2, 64));
      m0 = fmaxf(m0, __shfl_xor(m0, 4, 64));
      m0 = fmaxf(m0, __shfl_xor(m0, 8, 64));
      if (lr == 0) wmaxL[(i * 16 + quad * 4 + r) * 4 + wave] = m0;
    }

  {  // stage V transposed: Vt[d][c*64+kk]
    int kk = t & 63, dc0 = t >> 6;
#pragma unroll
    for (int c = 0; c < 4; ++c) {
      const unsigned short* Vg = V + bh + (size_t)kb[c] * 4096 + (size_t)kk * 64;
#pragma unroll
      for (int rr = 0; rr < 2; ++rr) {
        int dc = dc0 + rr * 4;
        s16x8 vv = *(const s16x8*)(Vg + dc * 8);
#pragma unroll
        for (int e = 0; e < 8; ++e)
          *(unsigned short*)(Vt + (dc * 8 + e) * 528 + (c * 64 + kk) * 2) = vv[e];
      }
    }
  }
  __syncthreads();  // B1: wmax + Vt visible

  // global max, exp (in place), row sums -> wsumL, P -> LDS (bf16)
#pragma unroll
  for (int i = 0; i < 4; ++i)
#pragma unroll
    for (int r = 0; r < 4; ++r) {
      int row = i * 16 + quad * 4 + r;
      f32x4 wmv = *(const f32x4*)(wmaxL + row * 4);
      float g = fmaxf(fmaxf(wmv[0], wmv[1]), fmaxf(wmv[2], wmv[3]));
      float sm = 0.f;
#pragma unroll
      for (int j = 0; j < 4; ++j) {
        float e = __expf(s[i][j][r] - g);
        s[i][j][r] = e;
        sm += e;
      }
      sm += __shfl_xor(sm, 1, 64);
      sm += __shfl_xor(sm, 2, 64);
      sm += __shfl_xor(sm, 4, 64);
      sm += __shfl_xor(sm, 8, 64);
      if (lr == 0) wsumL[row * 4 + wave] = sm;
    }
#pragma unroll
  for (int i = 0; i < 4; ++i)
#pragma unroll
    for (int r = 0; r < 4; ++r) {
      char* prow = Pb + (i * 16 + quad * 4 + r) * 528 + wave * 128 + lr * 2;
#pragma unroll
      for (int j = 0; j < 4; ++j) *(unsigned short*)(prow + j * 32) = f2b(s[i][j][r]);
    }
  __syncthreads();  // B2: P + wsum visible

  // ---- PV: wave handles query rows [wave*16, wave*16+16) ----
  f32x4 acc2[4] = {};
  const char* Prow = Pb + (wave * 16 + lr) * 528;
#pragma unroll
  for (int ks = 0; ks < 8; ++ks) {
    s16x8 a = *(const s16x8*)(Prow + ks * 64 + quad * 16);
#pragma unroll
    for (int j = 0; j < 4; ++j) {
      s16x8 bb2 = *(const s16x8*)(Vt + (j * 16 + lr) * 528 + ks * 64 + quad * 16);
      acc2[j] = __builtin_amdgcn_mfma_f32_16x16x32_bf16(a, bb2, acc2[j], 0, 0, 0);
    }
  }
  float inv[4];
#pragma unroll
  for (int r = 0; r < 4; ++r) {
    int row = wave * 16 + quad * 4 + r;
    f32x4 wsv = *(const f32x4*)(wsumL + row * 4);
    inv[r] = 1.0f / (wsv[0] + wsv[1] + wsv[2] + wsv[3]);
  }
#pragma unroll
  for (int r = 0; r < 4; ++r) {
    size_t srow = (size_t)qi * 64 + wave * 16 + quad * 4 + r;
    size_t base = ((size_t)b * 4096 + srow) * 1024 + h * 64;
#pragma unroll
    for (int j = 0; j < 4; ++j) ctx[base + j * 16 + lr] = f2b(acc2[j][r] * inv[r]);
  }
}

// ----------------------------- layernorm -----------------------------------
__global__ __launch_bounds__(256) void lnorm(float* __restrict__ y,
                                             const float* __restrict__ g,
                                             const float* __restrict__ bta) {
  __shared__ float red[8];
  float4* p = (float4*)(y + (size_t)blockIdx.x * 1024);
  float4 v = p[threadIdx.x];
  float s1 = v.x + v.y + v.z + v.w;
  float s2 = v.x * v.x + v.y * v.y + v.z * v.z + v.w * v.w;
#pragma unroll
  for (int m = 1; m <= 32; m <<= 1) {
    s1 += __shfl_xor(s1, m, 64);
    s2 += __shfl_xor(s2, m, 64);
  }
  int wv = threadIdx.x >> 6;
  if ((threadIdx.x & 63) == 0) {
    red[wv] = s1;
    red[4 + wv] = s2;
  }
  __syncthreads();
  float t1 = red[0] + red[1] + red[2] + red[3];
  float t2 = red[4] + red[5] + red[6] + red[7];
  float mu = t1 * (1.0f / 1024.0f);
  float var = t2 * (1.0f / 1024.0f) - mu * mu;
  float rs = rsqrtf(var + 1e-12f);
  float4 gg = ((const float4*)g)[threadIdx.x];
  float4 bb = ((const float4*)bta)[threadIdx.x];
  float4 o;
  o.x = (v.x - mu) * rs * gg.x + bb.x;
  o.y = (v.y - mu) * rs * gg.y + bb.y;
  o.z = (v.z - mu) * rs * gg.z + bb.z;
  o.w = (v.w - mu) * rs * gg.w + bb.w;
  p[threadIdx.x] = o;
}

// ----------------------------- launcher ------------------------------------
extern "C" void kernel_launch(void* const* d_in, const int* in_sizes, int n_in,
                              void* d_out, int out_size, void* d_ws, size_t ws_size,
                              hipStream_t stream) {
  (void)in_sizes; (void)n_in; (void)out_size; (void)ws_size;
  const float* hs = (const float*)d_in[0];
  const float* amask = (const float*)d_in[1];
  const float* wq = (const float*)d_in[2];
  const float* bq = (const float*)d_in[3];
  const float* wk = (const float*)d_in[4];
  const float* bk = (const float*)d_in[5];
  const float* wv = (const float*)d_in[6];
  const float* bv = (const float*)d_in[7];
  const float* wo = (const float*)d_in[8];
  const float* bo = (const float*)d_in[9];
  const float* lg = (const float*)d_in[10];
  const float* lb = (const float*)d_in[11];

  char* ws = (char*)d_ws;  // needs ~168 MB
  unsigned short* hbf = (unsigned short*)(ws);                 // 32 MB  [16384][1024]
  unsigned short* wqb = (unsigned short*)(ws + 33554432);      // 4 x 2 MB (q,k,v,o)
  unsigned short* qb  = (unsigned short*)(ws + 41943040);      // 32 MB  [b][h][s][d]
  unsigned short* kbb = (unsigned short*)(ws + 75497472);      // 32 MB
  unsigned short* vbb = (unsigned short*)(ws + 109051904);     // 32 MB
  unsigned short* cxb = (unsigned short*)(ws + 142606336);     // 32 MB  [b][s][1024]
  unsigned short* wkb = wqb + 1048576;
  unsigned short* wvb = wkb + 1048576;
  unsigned short* wob = wvb + 1048576;
  float* out = (float*)d_out;

  cast_hidden<<<16384, 256, 0, stream>>>(hs, hbf);
  cast_weights<<<dim3(1024, 4), 256, 0, stream>>>(wq, wk, wv, wo, wqb);

  dim3 gg(128, 8);
  gemm128<0><<<gg, 256, 0, stream>>>(hbf, wqb, bq, nullptr, qb);
  gemm128<0><<<gg, 256, 0, stream>>>(hbf, wkb, bk, nullptr, kbb);
  gemm128<0><<<gg, 256, 0, stream>>>(hbf, wvb, bv, nullptr, vbb);

  attn<<<dim3(64, 16, 4), 256, 0, stream>>>(qb, kbb, vbb, amask, cxb);

  gemm128<1><<<gg, 256, 0, stream>>>(cxb, wob, bo, hs, (void*)out);
  lnorm<<<16384, 256, 0, stream>>>(out, lg, lb);
}